// Round 4
// baseline (212.884 us; speedup 1.0000x reference)
//
#include <hip/hip_runtime.h>
#include <cstdint>
#include <cstddef>

typedef _Float16 h8_t __attribute__((ext_vector_type(8)));
typedef _Float16 h4_t __attribute__((ext_vector_type(4)));
typedef float f32x4 __attribute__((ext_vector_type(4)));
typedef float f32x16 __attribute__((ext_vector_type(16)));
typedef unsigned u32x4 __attribute__((ext_vector_type(4)));

#define MFMA_16x16x32_F16(a, b, c) __builtin_amdgcn_mfma_f32_16x16x32_f16(a, b, c, 0, 0, 0)
#define MFMA_32x32x16_F16(a, b, c) __builtin_amdgcn_mfma_f32_32x32x16_f16(a, b, c, 0, 0, 0)

__device__ inline void gload_lds16(const void* g, void* l) {
  __builtin_amdgcn_global_load_lds((const __attribute__((address_space(1))) void*)g,
                                   (__attribute__((address_space(3))) void*)l, 16, 0, 0);
}

#define CFENCE asm volatile("" ::: "memory")
#define BAR() do { CFENCE; __builtin_amdgcn_s_barrier(); CFENCE; } while (0)

// ---------------- convert f32 -> f16 ----------------
__global__ void cvt_f16_kernel(const float* __restrict__ in, _Float16* __restrict__ out, int n4) {
  int i = blockIdx.x * 256 + threadIdx.x;
  if (i >= n4) return;
  float4 v = reinterpret_cast<const float4*>(in)[i];
  h4_t h;
  h[0] = (_Float16)v.x; h[1] = (_Float16)v.y; h[2] = (_Float16)v.z; h[3] = (_Float16)v.w;
  reinterpret_cast<h4_t*>(out)[i] = h;
}

// ---------------- transpose + convert: in[R][Cc] f32 -> out[Cc][R] f16 ----------------
__global__ void transpose_cvt_kernel(const float* __restrict__ in, _Float16* __restrict__ out,
                                     int R, int Cc) {
  __shared__ float tile[32][33];
  int tx = threadIdx.x & 31;
  int ty = threadIdx.x >> 5;
  int c0 = blockIdx.x * 32;
  int r0 = blockIdx.y * 32;
#pragma unroll
  for (int i = 0; i < 4; ++i)
    tile[ty + i * 8][tx] = in[(size_t)(r0 + ty + i * 8) * Cc + (c0 + tx)];
  __syncthreads();
#pragma unroll
  for (int i = 0; i < 4; ++i)
    out[(size_t)(c0 + ty + i * 8) * R + (r0 + tx)] = (_Float16)tile[tx][ty + i * 8];
}

// ---------------- 256-wide 8-phase GEMM (T1+T3+T4+T5; conflict-free fragment-major LDS) ----
// C[m][n] = sum_k A[m][k]*Bt[n][k] + bias[n].  A:[M][1024] f16, Bt:[N][1024] f16, K=1024.
// BM=256, BN template (256 or 128), BK=64, 512 threads = 8 waves (2 wm x 4 wn).
// Per-wave output: 128 x BN/4. K-tile = 4 phases x 16(or 8) MFMA; counted vmcnt, never 0 in-loop.
// LDS layout is fragment-major: slot (g,kk,q,l) holds A[row=g*16+l][k0+kk*32+q*8..+7]; a wave's
// ds_read_b128 is base+lane*16 (conflict-free). Staged via global_load_lds with permuted
// global source (linear LDS dest), per m173.
template <int BN, int EPI>
__global__ __launch_bounds__(512, 2) void gemm8p_kernel(
    const _Float16* __restrict__ A, const _Float16* __restrict__ Bt,
    const float* __restrict__ bias, _Float16* __restrict__ outQ,
    _Float16* __restrict__ outK, _Float16* __restrict__ outV,
    float* __restrict__ outF, int NB) {
  constexpr int NREP = BN / 64;                 // B fragments per wave (4 or 2)
  constexpr int BLOADS = (BN == 256) ? 2 : 1;   // B stage units per K-tile
  __shared__ _Float16 Al[2][16384];
  __shared__ _Float16 Bl[2][BN * 64];

  const int tid = threadIdx.x;
  const int lane = tid & 63;
  const int w = tid >> 6;
  const int wm = w >> 2, wn = w & 3;

  int wg = blockIdx.x;
  const int cpx = gridDim.x >> 3;               // blocks per XCD (grid % 8 == 0)
  wg = (wg & 7) * cpx + (wg >> 3);
  const int bm = wg / NB, bn = wg % NB;
  const int m0 = bm * 256;
  const int n0 = bn * BN;

  f32x4 acc[8][NREP];
#pragma unroll
  for (int m = 0; m < 8; ++m)
#pragma unroll
    for (int n = 0; n < NREP; ++n) acc[m][n] = (f32x4){0.f, 0.f, 0.f, 0.f};

  auto stageA = [&](int buf, int k0, int u) {
#pragma unroll
    for (int it = 0; it < 2; ++it) {
      const int s = u * 1024 + it * 512 + tid;
      gload_lds16(&A[(size_t)(m0 + ((s >> 7) << 4) + (s & 15)) * 1024 +
                     k0 + ((s >> 6) & 1) * 32 + ((s >> 4) & 3) * 8],
                  &Al[buf][s * 8]);
    }
  };
  auto stageB = [&](int buf, int k0, int u) {
#pragma unroll
    for (int it = 0; it < 2; ++it) {
      const int s = u * 1024 + it * 512 + tid;
      gload_lds16(&Bt[(size_t)(n0 + ((s >> 7) << 4) + (s & 15)) * 1024 +
                      k0 + ((s >> 6) & 1) * 32 + ((s >> 4) & 3) * 8],
                  &Bl[buf][s * 8]);
    }
  };

  // prologue: stage K-tiles 0 and 1
  stageA(0, 0, 0); stageA(0, 0, 1);
  stageB(0, 0, 0); if (BLOADS == 2) stageB(0, 0, 1);
  stageA(1, 64, 0); stageA(1, 64, 1);
  stageB(1, 64, 0); if (BLOADS == 2) stageB(1, 64, 1);
  if constexpr (BLOADS == 2) asm volatile("s_waitcnt vmcnt(8)" ::: "memory");
  else asm volatile("s_waitcnt vmcnt(6)" ::: "memory");
  BAR();

  h8_t afr[8][2], bfr[NREP][2];

#define QUAD(MH, NLO)                                                        \
  _Pragma("unroll") for (int m = 0; m < 4; ++m)                              \
  _Pragma("unroll") for (int n = 0; n < NREP / 2; ++n)                       \
  _Pragma("unroll") for (int kk = 0; kk < 2; ++kk)                           \
    acc[(MH)*4 + m][(NLO) + n] =                                             \
        MFMA_16x16x32_F16(afr[(MH)*4 + m][kk], bfr[(NLO) + n][kk],           \
                          acc[(MH)*4 + m][(NLO) + n]);

#pragma unroll 1
  for (int t = 0; t < 16; ++t) {
    const int buf = t & 1;
    const int kn = (t + 2) * 64;
    const bool st = (t + 2) < 16;
    const _Float16* Ab = &Al[buf][0];
    const _Float16* Bb = &Bl[buf][0];

    // ---- P0: ds_read all A frags + low-B frags; MFMA (m0..3 x lowN)
#pragma unroll
    for (int m = 0; m < 8; ++m)
#pragma unroll
      for (int kk = 0; kk < 2; ++kk)
        afr[m][kk] = *(const h8_t*)&Ab[(((wm * 8 + m) * 2 + kk) * 64 + lane) * 8];
#pragma unroll
    for (int n = 0; n < NREP / 2; ++n)
#pragma unroll
      for (int kk = 0; kk < 2; ++kk)
        bfr[n][kk] = *(const h8_t*)&Bb[(((wn * NREP + n) * 2 + kk) * 64 + lane) * 8];
    BAR();
    asm volatile("s_waitcnt lgkmcnt(0)" ::: "memory");
    __builtin_amdgcn_sched_barrier(0);
    __builtin_amdgcn_s_setprio(1);
    QUAD(0, 0)
    __builtin_amdgcn_s_setprio(0);
    BAR();

    // ---- P1: stage A halves of K-tile t+2; MFMA (m4..7 x lowN)
    if (st) { stageA(buf, kn, 0); stageA(buf, kn, 1); }
    BAR();
    __builtin_amdgcn_s_setprio(1);
    QUAD(1, 0)
    __builtin_amdgcn_s_setprio(0);
    BAR();

    // ---- P2: ds_read high-B frags; MFMA (m0..3 x highN)
#pragma unroll
    for (int n = NREP / 2; n < NREP; ++n)
#pragma unroll
      for (int kk = 0; kk < 2; ++kk)
        bfr[n][kk] = *(const h8_t*)&Bb[(((wn * NREP + n) * 2 + kk) * 64 + lane) * 8];
    BAR();
    asm volatile("s_waitcnt lgkmcnt(0)" ::: "memory");
    __builtin_amdgcn_sched_barrier(0);
    __builtin_amdgcn_s_setprio(1);
    QUAD(0, NREP / 2)
    __builtin_amdgcn_s_setprio(0);
    BAR();

    // ---- P3: stage B of K-tile t+2; MFMA (m4..7 x highN); counted vmcnt
    if (st) { stageB(buf, kn, 0); if (BLOADS == 2) stageB(buf, kn, 1); }
    BAR();
    __builtin_amdgcn_s_setprio(1);
    QUAD(1, NREP / 2)
    __builtin_amdgcn_s_setprio(0);
    if (st) {
      if constexpr (BLOADS == 2) asm volatile("s_waitcnt vmcnt(8)" ::: "memory");
      else asm volatile("s_waitcnt vmcnt(6)" ::: "memory");
    } else {
      asm volatile("s_waitcnt vmcnt(0)" ::: "memory");
    }
    BAR();
  }
#undef QUAD

  // ---- epilogue
#pragma unroll
  for (int m = 0; m < 8; ++m) {
#pragma unroll
    for (int n = 0; n < NREP; ++n) {
      const int gn = n0 + wn * (BN / 4) + n * 16 + (lane & 15);
      const int tm0 = m0 + wm * 128 + m * 16 + (lane >> 4) * 4;
      const float bv = bias[gn];
      if (EPI == 0) {
        const int which = gn >> 10;  // 0=Q 1=K 2=V
        const int nn = gn & 1023;
        const int hh = nn >> 6, d = nn & 63;
        const int t0 = tm0 & 2047, b = tm0 >> 11;
        const int bh = b * 16 + hh;
        if (which == 2) {
          h4_t pack;
#pragma unroll
          for (int r = 0; r < 4; ++r) pack[r] = (_Float16)(acc[m][n][r] + bv);
          *reinterpret_cast<h4_t*>(&outV[((size_t)bh * 64 + d) * 2048 + t0]) = pack;
        } else {
          _Float16* dst = (which == 0) ? outQ : outK;
          // Q pre-scaled by log2(e)/sqrt(D) so attention can use exp2 directly
          const float scale = (which == 0) ? 0.18033688011112042f : 1.0f;
#pragma unroll
          for (int r = 0; r < 4; ++r)
            dst[((size_t)bh * 2048 + t0 + r) * 64 + d] = (_Float16)((acc[m][n][r] + bv) * scale);
        }
      } else {
#pragma unroll
        for (int r = 0; r < 4; ++r)
          outF[(size_t)(tm0 + r) * 1024 + gn] = acc[m][n][r] + bv;
      }
    }
  }
}

// ---------------- flash attention (causal), swapped-QK in-register softmax ----------------
__device__ inline void stage_kv(const _Float16* __restrict__ Kbh, const _Float16* __restrict__ Vbh,
                                int kt, _Float16* Kd, _Float16* Vd, int w, int lane) {
  const _Float16* Kg = Kbh + (size_t)kt * 64 * 64;
  const _Float16* Vg = Vbh + kt * 64;
#pragma unroll
  for (int c = 0; c < 2; ++c) {
    const int idx = (2 * w + c) * 64 + lane;
    const int row = idx >> 3;
    const int chs = (idx & 7) ^ (row & 7);  // pre-swizzled global source (T2 via m173)
    gload_lds16(Kg + row * 64 + chs * 8, Kd + idx * 8);
    gload_lds16(Vg + (size_t)row * 2048 + chs * 8, Vd + idx * 8);
  }
}

// pack 16 exp'd f32 into 2 PV B-fragments
__device__ inline void pack_pfrag(const float* e, h8_t* out) {
  unsigned u[8];
#pragma unroll
  for (int i = 0; i < 8; ++i) {
    auto hv = __builtin_amdgcn_cvt_pkrtz(e[2 * i], e[2 * i + 1]);
    u[i] = __builtin_bit_cast(unsigned, hv);
  }
  auto r02 = __builtin_amdgcn_permlane32_swap(u[0], u[2], false, false);
  auto r13 = __builtin_amdgcn_permlane32_swap(u[1], u[3], false, false);
  auto r46 = __builtin_amdgcn_permlane32_swap(u[4], u[6], false, false);
  auto r57 = __builtin_amdgcn_permlane32_swap(u[5], u[7], false, false);
  u32x4 w0 = {(unsigned)r02[0], (unsigned)r13[0], (unsigned)r02[1], (unsigned)r13[1]};
  u32x4 w1 = {(unsigned)r46[0], (unsigned)r57[0], (unsigned)r46[1], (unsigned)r57[1]};
  out[0] = __builtin_bit_cast(h8_t, w0);
  out[1] = __builtin_bit_cast(h8_t, w1);
}

__global__ __launch_bounds__(256, 2) void attn_kernel(
    const _Float16* __restrict__ Q, const _Float16* __restrict__ K,
    const _Float16* __restrict__ Vt, _Float16* __restrict__ O) {
  __shared__ _Float16 Kl[2][64 * 64];
  __shared__ _Float16 Vl[2][64 * 64];
  const int tid = threadIdx.x;
  const int lane = tid & 63;
  const int w = tid >> 6;
  const int hi = lane >> 5;
  const int l31 = lane & 31;
  const int bh = blockIdx.x >> 3;
  const int pr = blockIdx.x & 7;
  const int b = bh >> 4, h = bh & 15;
  const _Float16* Kbh = K + (size_t)bh * 2048 * 64;
  const _Float16* Vbh = Vt + (size_t)bh * 64 * 2048;

#pragma unroll
  for (int gi = 0; gi < 2; ++gi) {
    const int g = gi ? (15 - pr) : pr;
    const int nt = 2 * g + 2;
    const int qbase = g * 128 + w * 32;
    const int qrow = qbase + l31;

    h8_t qf[4];
    const _Float16* Qp = Q + ((size_t)bh * 2048 + qrow) * 64 + hi * 8;
#pragma unroll
    for (int ds = 0; ds < 4; ++ds)
      qf[ds] = *reinterpret_cast<const h8_t*>(Qp + ds * 16);

    f32x16 oa[2] = {};
    float m = -1e30f, lsum = 0.f;

    stage_kv(Kbh, Vbh, 0, &Kl[0][0], &Vl[0][0], w, lane);
    __syncthreads();

    for (int kt = 0; kt < nt; ++kt) {
      const int cur = kt & 1;
      if (kt + 1 < nt)
        stage_kv(Kbh, Vbh, kt + 1, &Kl[cur ^ 1][0], &Vl[cur ^ 1][0], w, lane);

      if (kt * 64 <= qbase + 31) {
        const char* Kb = (const char*)&Kl[cur][0];
        const char* Vb = (const char*)&Vl[cur][0];
        f32x16 s0 = {}, s1 = {};
#pragma unroll
        for (int ds = 0; ds < 4; ++ds) {
          const int bc = ds * 32 + hi * 16;
          h8_t kf0 = *(const h8_t*)(Kb + l31 * 128 + (bc ^ ((l31 & 7) << 4)));
          h8_t kf1 = *(const h8_t*)(Kb + (32 + l31) * 128 + (bc ^ ((l31 & 7) << 4)));
          s0 = MFMA_32x32x16_F16(kf0, qf[ds], s0);
          s1 = MFMA_32x32x16_F16(kf1, qf[ds], s1);
        }
        if (kt >= 2 * g) {
#pragma unroll
          for (int r = 0; r < 16; ++r) {
            const int kr = kt * 64 + (r & 3) + 8 * (r >> 2) + 4 * hi;
            if (kr > qrow) s0[r] = -1e30f;
            if (kr + 32 > qrow) s1[r] = -1e30f;
          }
        }
        float t[16];
#pragma unroll
        for (int r = 0; r < 16; ++r) t[r] = fmaxf(s0[r], s1[r]);
#pragma unroll
        for (int st = 8; st >= 1; st >>= 1)
#pragma unroll
          for (int r = 0; r < st; ++r) t[r] = fmaxf(t[r], t[r + st]);
        const float pmax = fmaxf(t[0], __shfl_xor(t[0], 32));
        const float mnew = fmaxf(m, pmax);
        if (__any(mnew > m + 8.f)) {
          const float al = __builtin_amdgcn_exp2f(m - mnew);
          lsum *= al;
#pragma unroll
          for (int r = 0; r < 16; ++r) { oa[0][r] *= al; oa[1][r] *= al; }
          m = mnew;
        }
        float e0[16], e1[16];
#pragma unroll
        for (int r = 0; r < 16; ++r) {
          e0[r] = __builtin_amdgcn_exp2f(s0[r] - m);
          e1[r] = __builtin_amdgcn_exp2f(s1[r] - m);
        }
        float ps = 0.f;
#pragma unroll
        for (int r = 0; r < 16; ++r) ps += e0[r] + e1[r];
        ps += __shfl_xor(ps, 32);
        lsum += ps;
        h8_t pf[4];
        pack_pfrag(e0, pf + 0);
        pack_pfrag(e1, pf + 2);
#pragma unroll
        for (int dt = 0; dt < 2; ++dt) {
#pragma unroll
          for (int kg = 0; kg < 4; ++kg) {
            const int row = dt * 32 + l31;
            const int bc = kg * 32 + hi * 16;
            h8_t vf = *(const h8_t*)(Vb + row * 128 + (bc ^ ((row & 7) << 4)));
            oa[dt] = MFMA_32x32x16_F16(vf, pf[kg], oa[dt]);
          }
        }
      }
      __syncthreads();
    }

    const float inv = __builtin_amdgcn_rcpf(lsum);
    _Float16* Op = O + ((size_t)b * 2048 + qrow) * 1024 + h * 64;
#pragma unroll
    for (int dt = 0; dt < 2; ++dt) {
#pragma unroll
      for (int rg = 0; rg < 4; ++rg) {
        h4_t pk4;
#pragma unroll
        for (int i = 0; i < 4; ++i) pk4[i] = (_Float16)(oa[dt][rg * 4 + i] * inv);
        *reinterpret_cast<h4_t*>(Op + dt * 32 + rg * 8 + hi * 4) = pk4;
      }
    }
  }
}

extern "C" void kernel_launch(void* const* d_in, const int* in_sizes, int n_in,
                              void* d_out, int out_size, void* d_ws, size_t ws_size,
                              hipStream_t stream) {
  (void)in_sizes; (void)n_in; (void)out_size; (void)ws_size;
  const float* x = (const float*)d_in[0];
  const float* w_qkv = (const float*)d_in[1];
  const float* b_qkv = (const float*)d_in[2];
  const float* w_out = (const float*)d_in[3];
  const float* b_out = (const float*)d_in[4];
  float* out = (float*)d_out;

  char* ws = (char*)d_ws;
  size_t off = 0;
  auto alloc = [&](size_t bytes) {
    void* p = ws + off;
    off += (bytes + 255) & ~(size_t)255;
    return p;
  };
  _Float16* x16 = (_Float16*)alloc((size_t)8192 * 1024 * 2);
  _Float16* wqkvT = (_Float16*)alloc((size_t)3072 * 1024 * 2);
  _Float16* woutT = (_Float16*)alloc((size_t)1024 * 1024 * 2);
  _Float16* Qh = (_Float16*)alloc((size_t)64 * 2048 * 64 * 2);
  _Float16* Kh = (_Float16*)alloc((size_t)64 * 2048 * 64 * 2);
  _Float16* Vth = (_Float16*)alloc((size_t)64 * 64 * 2048 * 2);
  _Float16* Oh = (_Float16*)alloc((size_t)8192 * 1024 * 2);

  cvt_f16_kernel<<<8192, 256, 0, stream>>>(x, x16, 8192 * 1024 / 4);
  transpose_cvt_kernel<<<dim3(3072 / 32, 1024 / 32), 256, 0, stream>>>(w_qkv, wqkvT, 1024, 3072);
  transpose_cvt_kernel<<<dim3(1024 / 32, 1024 / 32), 256, 0, stream>>>(w_out, woutT, 1024, 1024);
  gemm8p_kernel<256, 0><<<384, 512, 0, stream>>>(x16, wqkvT, b_qkv, Qh, Kh, Vth, nullptr, 12);
  attn_kernel<<<64 * 8, 256, 0, stream>>>(Qh, Kh, Vth, Oh);
  gemm8p_kernel<128, 1><<<256, 512, 0, stream>>>(Oh, woutT, b_out, nullptr, nullptr, nullptr, out, 8);
}

// Round 5
// 194.544 us; speedup vs baseline: 1.0943x; 1.0943x over previous
//
#include <hip/hip_runtime.h>
#include <cstdint>
#include <cstddef>

typedef _Float16 h8_t __attribute__((ext_vector_type(8)));
typedef _Float16 h4_t __attribute__((ext_vector_type(4)));
typedef float f32x4 __attribute__((ext_vector_type(4)));
typedef float f32x16 __attribute__((ext_vector_type(16)));
typedef unsigned u32x4 __attribute__((ext_vector_type(4)));

#define MFMA_16x16x32_F16(a, b, c) __builtin_amdgcn_mfma_f32_16x16x32_f16(a, b, c, 0, 0, 0)
#define MFMA_32x32x16_F16(a, b, c) __builtin_amdgcn_mfma_f32_32x32x16_f16(a, b, c, 0, 0, 0)

__device__ inline void gload_lds16(const void* g, void* l) {
  __builtin_amdgcn_global_load_lds((const __attribute__((address_space(1))) void*)g,
                                   (__attribute__((address_space(3))) void*)l, 16, 0, 0);
}

#define CFENCE asm volatile("" ::: "memory")
#define BAR() do { CFENCE; __builtin_amdgcn_s_barrier(); CFENCE; } while (0)

// ---------------- convert f32 -> f16 ----------------
__global__ void cvt_f16_kernel(const float* __restrict__ in, _Float16* __restrict__ out, int n4) {
  int i = blockIdx.x * 256 + threadIdx.x;
  if (i >= n4) return;
  float4 v = reinterpret_cast<const float4*>(in)[i];
  h4_t h;
  h[0] = (_Float16)v.x; h[1] = (_Float16)v.y; h[2] = (_Float16)v.z; h[3] = (_Float16)v.w;
  reinterpret_cast<h4_t*>(out)[i] = h;
}

// ---------------- transpose + convert: in[R][Cc] f32 -> out[Cc][R] f16 ----------------
__global__ void transpose_cvt_kernel(const float* __restrict__ in, _Float16* __restrict__ out,
                                     int R, int Cc) {
  __shared__ float tile[32][33];
  int tx = threadIdx.x & 31;
  int ty = threadIdx.x >> 5;
  int c0 = blockIdx.x * 32;
  int r0 = blockIdx.y * 32;
#pragma unroll
  for (int i = 0; i < 4; ++i)
    tile[ty + i * 8][tx] = in[(size_t)(r0 + ty + i * 8) * Cc + (c0 + tx)];
  __syncthreads();
#pragma unroll
  for (int i = 0; i < 4; ++i)
    out[(size_t)(c0 + ty + i * 8) * R + (r0 + tx)] = (_Float16)tile[tx][ty + i * 8];
}

// ---------------- 256x128 GEMM, triple-buffered BK=64, 2 phases/K-tile ----------------
// C[m][n] = sum_k A[m][k]*Bt[n][k] + bias[n]. A:[M][1024], Bt:[N][1024] f16, K=1024.
// 512 threads = 8 waves (4 wm x 2 wn), per-wave 64x64 output (acc[4][4]).
// LDS fragment-major (conflict-free by construction, proven 0 conflicts in R4):
//   slot s=(g*2+kk)*64+lane holds T[g*16+(lane&15)][k0+kk*32+((lane>>4)&3)*8 ..+7].
// Per phase: <=12 ds_read_b128 || 2-4 global_load_lds issues -> bar -> lgkmcnt(0) ->
// setprio(1) 16 MFMA setprio(0) -> bar.  vmcnt(6) once per K-tile (counted, not 0).
template <int EPI>
__global__ __launch_bounds__(512, 2) void gemm4p_kernel(
    const _Float16* __restrict__ A, const _Float16* __restrict__ Bt,
    const float* __restrict__ bias, _Float16* __restrict__ outQ,
    _Float16* __restrict__ outK, _Float16* __restrict__ outV,
    float* __restrict__ outF, int NB) {
  __shared__ _Float16 Al[3][16384];  // 256x64 per buf
  __shared__ _Float16 Bl[3][8192];   // 128x64 per buf

  const int tid = threadIdx.x;
  const int lane = tid & 63;
  const int w = tid >> 6;
  const int wm = w >> 1, wn = w & 1;

  int wg = blockIdx.x;
  const int cpx = gridDim.x >> 3;  // grid % 8 == 0
  wg = (wg & 7) * cpx + (wg >> 3);
  const int bm = wg / NB, bn = wg % NB;
  const int m0 = bm * 256;
  const int n0 = bn * 128;

  f32x4 acc[4][4];
#pragma unroll
  for (int m = 0; m < 4; ++m)
#pragma unroll
    for (int n = 0; n < 4; ++n) acc[m][n] = (f32x4){0.f, 0.f, 0.f, 0.f};

  // slot s -> row (s>>7)*16 + (s&15), k-chunk ((s>>6)&1)*32 + ((s>>4)&3)*8
  auto stageA = [&](int buf, int k0, int u) {
#pragma unroll
    for (int it = 0; it < 2; ++it) {
      const int s = u * 1024 + it * 512 + tid;
      gload_lds16(&A[(size_t)(m0 + ((s >> 7) << 4) + (s & 15)) * 1024 +
                     k0 + ((s >> 6) & 1) * 32 + ((s >> 4) & 3) * 8],
                  &Al[buf][s * 8]);
    }
  };
  auto stageB = [&](int buf, int k0) {
#pragma unroll
    for (int it = 0; it < 2; ++it) {
      const int s = it * 512 + tid;
      gload_lds16(&Bt[(size_t)(n0 + ((s >> 7) << 4) + (s & 15)) * 1024 +
                      k0 + ((s >> 6) & 1) * 32 + ((s >> 4) & 3) * 8],
                  &Bl[buf][s * 8]);
    }
  };

  // prologue: stage K-tiles 0 and 1; wait tile 0 (6 of tile 1 stay in flight)
  stageA(0, 0, 0); stageA(0, 0, 1); stageB(0, 0);
  stageA(1, 64, 0); stageA(1, 64, 1); stageB(1, 64);
  asm volatile("s_waitcnt vmcnt(6)" ::: "memory");
  BAR();

  h8_t af[4][2], bf[4][2];

#pragma unroll 1
  for (int t = 0; t < 16; ++t) {
    const int buf = t % 3;
    const int nbuf = (t + 2) % 3;
    const int kn = (t + 2) * 64;
    const bool st = (t + 2) < 16;
    const _Float16* Ab = &Al[buf][0];
    const _Float16* Bb = &Bl[buf][0];

    // ---- Phase A: read A(all) + B(low); stage A of t+2; MFMA m0-3 x n0-1
#pragma unroll
    for (int mf = 0; mf < 4; ++mf)
#pragma unroll
      for (int kk = 0; kk < 2; ++kk)
        af[mf][kk] = *(const h8_t*)&Ab[(((wm * 4 + mf) * 2 + kk) * 64 + lane) * 8];
#pragma unroll
    for (int nf = 0; nf < 2; ++nf)
#pragma unroll
      for (int kk = 0; kk < 2; ++kk)
        bf[nf][kk] = *(const h8_t*)&Bb[(((wn * 4 + nf) * 2 + kk) * 64 + lane) * 8];
    if (st) { stageA(nbuf, kn, 0); stageA(nbuf, kn, 1); }
    BAR();
    asm volatile("s_waitcnt lgkmcnt(0)" ::: "memory");
    __builtin_amdgcn_sched_barrier(0);
    __builtin_amdgcn_s_setprio(1);
#pragma unroll
    for (int mf = 0; mf < 4; ++mf)
#pragma unroll
      for (int nf = 0; nf < 2; ++nf)
#pragma unroll
        for (int kk = 0; kk < 2; ++kk)
          acc[mf][nf] = MFMA_16x16x32_F16(af[mf][kk], bf[nf][kk], acc[mf][nf]);
    __builtin_amdgcn_s_setprio(0);
    BAR();

    // ---- Phase B: read B(high); stage B of t+2; MFMA m0-3 x n2-3; counted vmcnt
#pragma unroll
    for (int nf = 2; nf < 4; ++nf)
#pragma unroll
      for (int kk = 0; kk < 2; ++kk)
        bf[nf][kk] = *(const h8_t*)&Bb[(((wn * 4 + nf) * 2 + kk) * 64 + lane) * 8];
    if (st) stageB(nbuf, kn);
    BAR();
    asm volatile("s_waitcnt lgkmcnt(0)" ::: "memory");
    __builtin_amdgcn_sched_barrier(0);
    __builtin_amdgcn_s_setprio(1);
#pragma unroll
    for (int mf = 0; mf < 4; ++mf)
#pragma unroll
      for (int nf = 2; nf < 4; ++nf)
#pragma unroll
        for (int kk = 0; kk < 2; ++kk)
          acc[mf][nf] = MFMA_16x16x32_F16(af[mf][kk], bf[nf][kk], acc[mf][nf]);
    __builtin_amdgcn_s_setprio(0);
    if (st) asm volatile("s_waitcnt vmcnt(6)" ::: "memory");
    else if (t + 1 < 16) asm volatile("s_waitcnt vmcnt(0)" ::: "memory");
    BAR();
  }

  // ---- epilogue
#pragma unroll
  for (int mf = 0; mf < 4; ++mf) {
#pragma unroll
    for (int nf = 0; nf < 4; ++nf) {
      const int gn = n0 + wn * 64 + nf * 16 + (lane & 15);
      const int tm0 = m0 + wm * 64 + mf * 16 + (lane >> 4) * 4;
      const float bv = bias[gn];
      if (EPI == 0) {
        const int which = gn >> 10;  // 0=Q 1=K 2=V
        const int nn = gn & 1023;
        const int hh = nn >> 6, d = nn & 63;
        const int t0 = tm0 & 2047, b = tm0 >> 11;
        const int bh = b * 16 + hh;
        if (which == 2) {
          h4_t pack;
#pragma unroll
          for (int r = 0; r < 4; ++r) pack[r] = (_Float16)(acc[mf][nf][r] + bv);
          *reinterpret_cast<h4_t*>(&outV[((size_t)bh * 64 + d) * 2048 + t0]) = pack;
        } else {
          _Float16* dst = (which == 0) ? outQ : outK;
          // Q pre-scaled by log2(e)/sqrt(D) so attention can use exp2 directly
          const float scale = (which == 0) ? 0.18033688011112042f : 1.0f;
#pragma unroll
          for (int r = 0; r < 4; ++r)
            dst[((size_t)bh * 2048 + t0 + r) * 64 + d] = (_Float16)((acc[mf][nf][r] + bv) * scale);
        }
      } else {
#pragma unroll
        for (int r = 0; r < 4; ++r)
          outF[(size_t)(tm0 + r) * 1024 + gn] = acc[mf][nf][r] + bv;
      }
    }
  }
}

// ---------------- flash attention (causal), swapped-QK in-register softmax ----------------
__device__ inline void stage_kv(const _Float16* __restrict__ Kbh, const _Float16* __restrict__ Vbh,
                                int kt, _Float16* Kd, _Float16* Vd, int w, int lane) {
  const _Float16* Kg = Kbh + (size_t)kt * 64 * 64;
  const _Float16* Vg = Vbh + kt * 64;
#pragma unroll
  for (int c = 0; c < 2; ++c) {
    const int idx = (2 * w + c) * 64 + lane;
    const int row = idx >> 3;
    const int chs = (idx & 7) ^ (row & 7);  // pre-swizzled global source (T2 via m173)
    gload_lds16(Kg + row * 64 + chs * 8, Kd + idx * 8);
    gload_lds16(Vg + (size_t)row * 2048 + chs * 8, Vd + idx * 8);
  }
}

// pack 16 exp'd f32 into 2 PV B-fragments
__device__ inline void pack_pfrag(const float* e, h8_t* out) {
  unsigned u[8];
#pragma unroll
  for (int i = 0; i < 8; ++i) {
    auto hv = __builtin_amdgcn_cvt_pkrtz(e[2 * i], e[2 * i + 1]);
    u[i] = __builtin_bit_cast(unsigned, hv);
  }
  auto r02 = __builtin_amdgcn_permlane32_swap(u[0], u[2], false, false);
  auto r13 = __builtin_amdgcn_permlane32_swap(u[1], u[3], false, false);
  auto r46 = __builtin_amdgcn_permlane32_swap(u[4], u[6], false, false);
  auto r57 = __builtin_amdgcn_permlane32_swap(u[5], u[7], false, false);
  u32x4 w0 = {(unsigned)r02[0], (unsigned)r13[0], (unsigned)r02[1], (unsigned)r13[1]};
  u32x4 w1 = {(unsigned)r46[0], (unsigned)r57[0], (unsigned)r46[1], (unsigned)r57[1]};
  out[0] = __builtin_bit_cast(h8_t, w0);
  out[1] = __builtin_bit_cast(h8_t, w1);
}

__global__ __launch_bounds__(256, 2) void attn_kernel(
    const _Float16* __restrict__ Q, const _Float16* __restrict__ K,
    const _Float16* __restrict__ Vt, _Float16* __restrict__ O) {
  __shared__ _Float16 Kl[2][64 * 64];
  __shared__ _Float16 Vl[2][64 * 64];
  const int tid = threadIdx.x;
  const int lane = tid & 63;
  const int w = tid >> 6;
  const int hi = lane >> 5;
  const int l31 = lane & 31;
  const int bh = blockIdx.x >> 3;
  const int pr = blockIdx.x & 7;
  const int b = bh >> 4, h = bh & 15;
  const _Float16* Kbh = K + (size_t)bh * 2048 * 64;
  const _Float16* Vbh = Vt + (size_t)bh * 64 * 2048;

#pragma unroll
  for (int gi = 0; gi < 2; ++gi) {
    const int g = gi ? (15 - pr) : pr;
    const int nt = 2 * g + 2;
    const int qbase = g * 128 + w * 32;
    const int qrow = qbase + l31;

    h8_t qf[4];
    const _Float16* Qp = Q + ((size_t)bh * 2048 + qrow) * 64 + hi * 8;
#pragma unroll
    for (int ds = 0; ds < 4; ++ds)
      qf[ds] = *reinterpret_cast<const h8_t*>(Qp + ds * 16);

    f32x16 oa[2] = {};
    float m = -1e30f, lsum = 0.f;

    stage_kv(Kbh, Vbh, 0, &Kl[0][0], &Vl[0][0], w, lane);
    __syncthreads();

    for (int kt = 0; kt < nt; ++kt) {
      const int cur = kt & 1;
      if (kt + 1 < nt)
        stage_kv(Kbh, Vbh, kt + 1, &Kl[cur ^ 1][0], &Vl[cur ^ 1][0], w, lane);

      if (kt * 64 <= qbase + 31) {
        const char* Kb = (const char*)&Kl[cur][0];
        const char* Vb = (const char*)&Vl[cur][0];
        f32x16 s0 = {}, s1 = {};
#pragma unroll
        for (int ds = 0; ds < 4; ++ds) {
          const int bc = ds * 32 + hi * 16;
          h8_t kf0 = *(const h8_t*)(Kb + l31 * 128 + (bc ^ ((l31 & 7) << 4)));
          h8_t kf1 = *(const h8_t*)(Kb + (32 + l31) * 128 + (bc ^ ((l31 & 7) << 4)));
          s0 = MFMA_32x32x16_F16(kf0, qf[ds], s0);
          s1 = MFMA_32x32x16_F16(kf1, qf[ds], s1);
        }
        if (kt >= 2 * g) {
#pragma unroll
          for (int r = 0; r < 16; ++r) {
            const int kr = kt * 64 + (r & 3) + 8 * (r >> 2) + 4 * hi;
            if (kr > qrow) s0[r] = -1e30f;
            if (kr + 32 > qrow) s1[r] = -1e30f;
          }
        }
        float t[16];
#pragma unroll
        for (int r = 0; r < 16; ++r) t[r] = fmaxf(s0[r], s1[r]);
#pragma unroll
        for (int st = 8; st >= 1; st >>= 1)
#pragma unroll
          for (int r = 0; r < st; ++r) t[r] = fmaxf(t[r], t[r + st]);
        const float pmax = fmaxf(t[0], __shfl_xor(t[0], 32));
        const float mnew = fmaxf(m, pmax);
        if (__any(mnew > m + 8.f)) {
          const float al = __builtin_amdgcn_exp2f(m - mnew);
          lsum *= al;
#pragma unroll
          for (int r = 0; r < 16; ++r) { oa[0][r] *= al; oa[1][r] *= al; }
          m = mnew;
        }
        float e0[16], e1[16];
#pragma unroll
        for (int r = 0; r < 16; ++r) {
          e0[r] = __builtin_amdgcn_exp2f(s0[r] - m);
          e1[r] = __builtin_amdgcn_exp2f(s1[r] - m);
        }
        float ps = 0.f;
#pragma unroll
        for (int r = 0; r < 16; ++r) ps += e0[r] + e1[r];
        ps += __shfl_xor(ps, 32);
        lsum += ps;
        h8_t pf[4];
        pack_pfrag(e0, pf + 0);
        pack_pfrag(e1, pf + 2);
#pragma unroll
        for (int dt = 0; dt < 2; ++dt) {
#pragma unroll
          for (int kg = 0; kg < 4; ++kg) {
            const int row = dt * 32 + l31;
            const int bc = kg * 32 + hi * 16;
            h8_t vf = *(const h8_t*)(Vb + row * 128 + (bc ^ ((row & 7) << 4)));
            oa[dt] = MFMA_32x32x16_F16(vf, pf[kg], oa[dt]);
          }
        }
      }
      __syncthreads();
    }

    const float inv = __builtin_amdgcn_rcpf(lsum);
    _Float16* Op = O + ((size_t)b * 2048 + qrow) * 1024 + h * 64;
#pragma unroll
    for (int dt = 0; dt < 2; ++dt) {
#pragma unroll
      for (int rg = 0; rg < 4; ++rg) {
        h4_t pk4;
#pragma unroll
        for (int i = 0; i < 4; ++i) pk4[i] = (_Float16)(oa[dt][rg * 4 + i] * inv);
        *reinterpret_cast<h4_t*>(Op + dt * 32 + rg * 8 + hi * 4) = pk4;
      }
    }
  }
}

extern "C" void kernel_launch(void* const* d_in, const int* in_sizes, int n_in,
                              void* d_out, int out_size, void* d_ws, size_t ws_size,
                              hipStream_t stream) {
  (void)in_sizes; (void)n_in; (void)out_size; (void)ws_size;
  const float* x = (const float*)d_in[0];
  const float* w_qkv = (const float*)d_in[1];
  const float* b_qkv = (const float*)d_in[2];
  const float* w_out = (const float*)d_in[3];
  const float* b_out = (const float*)d_in[4];
  float* out = (float*)d_out;

  char* ws = (char*)d_ws;
  size_t off = 0;
  auto alloc = [&](size_t bytes) {
    void* p = ws + off;
    off += (bytes + 255) & ~(size_t)255;
    return p;
  };
  _Float16* x16 = (_Float16*)alloc((size_t)8192 * 1024 * 2);
  _Float16* wqkvT = (_Float16*)alloc((size_t)3072 * 1024 * 2);
  _Float16* woutT = (_Float16*)alloc((size_t)1024 * 1024 * 2);
  _Float16* Qh = (_Float16*)alloc((size_t)64 * 2048 * 64 * 2);
  _Float16* Kh = (_Float16*)alloc((size_t)64 * 2048 * 64 * 2);
  _Float16* Vth = (_Float16*)alloc((size_t)64 * 64 * 2048 * 2);
  _Float16* Oh = (_Float16*)alloc((size_t)8192 * 1024 * 2);

  cvt_f16_kernel<<<8192, 256, 0, stream>>>(x, x16, 8192 * 1024 / 4);
  transpose_cvt_kernel<<<dim3(3072 / 32, 1024 / 32), 256, 0, stream>>>(w_qkv, wqkvT, 1024, 3072);
  transpose_cvt_kernel<<<dim3(1024 / 32, 1024 / 32), 256, 0, stream>>>(w_out, woutT, 1024, 1024);
  gemm4p_kernel<0><<<768, 512, 0, stream>>>(x16, wqkvT, b_qkv, Qh, Kh, Vth, nullptr, 24);
  attn_kernel<<<64 * 8, 256, 0, stream>>>(Qh, Kh, Vth, Oh);
  gemm4p_kernel<1><<<256, 512, 0, stream>>>(Oh, woutT, b_out, nullptr, nullptr, nullptr, out, 8);
}